// Round 7
// baseline (238.437 us; speedup 1.0000x reference)
//
#include <hip/hip_runtime.h>
#include <hip/hip_cooperative_groups.h>

namespace cg = cooperative_groups;

#define N_ENTITY 100000
#define D 128
#define HID 256
#define N_REL 48
#define N_BASES 8
#define N_EDGES 1000000
#define NPOS 1024
#define ECAP 96          // bucket capacity per slot (max in-deg of ~1019 targets ~35)
#define PCAP 8           // max duplicate positions per entity (P(>8) ~ 1e-16)
#define GRIDSZ 256
#define BLK 512
#define NTHREADS (GRIDSZ * BLK)   // 131072

// ws layout in 4-byte elements
#define OFF_MAP    0         // int[100032]  -> sentinel 0x7F7F7F7F
#define OFF_BITMAP 100032    // int[3200]    -> 0
#define OFF_UCNT   103232    // int[1024]    -> 0
#define OFF_PCNT   104256    // int[1024]    -> 0
#define OFF_PBUF   105280    // int[1024*PCAP]
#define OFF_BKT    113472    // int[1024*ECAP] packed (src | type<<17)
// end = 211776 ints ~ 0.85 MB

__global__ __launch_bounds__(BLK, 1) void k_mega(
        const int* __restrict__ srcp, const int* __restrict__ dstp,
        const int* __restrict__ etype, const int* __restrict__ eids,
        const float* __restrict__ x, const float* __restrict__ comp,
        const float* __restrict__ bases, const float* __restrict__ root,
        const float* __restrict__ bias, const float* __restrict__ w1,
        const float* __restrict__ b1, const float* __restrict__ w2,
        const float* __restrict__ b2, const float* __restrict__ wp,
        const float* __restrict__ bp, int* __restrict__ ws,
        float* __restrict__ out) {
    cg::grid_group grid = cg::this_grid();
    int* map            = ws + OFF_MAP;
    unsigned int* bmap  = (unsigned int*)(ws + OFF_BITMAP);
    int* ucnt           = ws + OFF_UCNT;
    int* pcnt           = ws + OFF_PCNT;
    int* pbuf           = ws + OFF_PBUF;
    int* bkt            = ws + OFF_BKT;

    int tid = threadIdx.x;
    int gtid = blockIdx.x * BLK + tid;

    // ---- Phase 0: clear map/bitmap/ucnt/pcnt (one element per thread) ----
    for (int i = gtid; i < 105280; i += NTHREADS)
        ws[i] = (i < 100032) ? 0x7F7F7F7F : 0;
    grid.sync();

    // ---- Phase 1: register targets ----
    if (gtid < NPOS) {
        int e = eids[gtid];
        atomicMin(&map[e], gtid);
        atomicOr(&bmap[e >> 5], 1u << (e & 31));
    }
    grid.sync();

    // ---- Phase 2: position lists + 1M-edge scan into buckets ----
    if (gtid < NPOS) {
        int u = map[eids[gtid]];
        int q = atomicAdd(&pcnt[u], 1);
        if (q < PCAP) pbuf[u * PCAP + q] = gtid;
    }
    for (int b = gtid; b < N_EDGES / 4; b += NTHREADS) {
        const int4 d4 = *reinterpret_cast<const int4*>(dstp + b * 4);
        #pragma unroll
        for (int q = 0; q < 4; ++q) {
            int d = (&d4.x)[q];
            if ((bmap[d >> 5] >> (d & 31)) & 1u) {
                int e = b * 4 + q;
                int u = map[d];
                int pos = atomicAdd(&ucnt[u], 1);
                if (pos < ECAP)
                    bkt[u * ECAP + pos] = srcp[e] | (etype[e] << 17);
            }
        }
    }
    grid.sync();

    // ---- Phase 3: fused RGCN + MLP + projection, 4 slots per block ----
    __shared__ float xs[4][D];                // 2 KB
    __shared__ float accs[4][N_BASES * D];    // 16 KB
    __shared__ float hs[4][D];                // 2 KB
    __shared__ float t1s[4][D / 2];           // 1 KB
    __shared__ float h2s[4][D];               // 2 KB
    __shared__ float part[8192];              // 32 KB K-split combine buffer
    __shared__ float ctab[ECAP][N_BASES];     // 3 KB
    __shared__ int esrc[ECAP], eti[ECAP];
    __shared__ int deg48[N_REL];
    __shared__ int enames[4], npos4[4], plist4[4][PCAP];

    int u0 = blockIdx.x * 4;
    if (tid < 4) {
        enames[tid] = eids[u0 + tid];
        int np = pcnt[u0 + tid];
        npos4[tid] = np < PCAP ? np : PCAP;
    }
    if (tid < 4 * PCAP) {
        int s = tid >> 3, q = tid & (PCAP - 1);
        plist4[s][q] = pbuf[(u0 + s) * PCAP + q];
    }
    __syncthreads();
    {
        int s = tid >> 7, dd = tid & 127;
        xs[s][dd] = x[(size_t)enames[s] * D + dd];
    }

    // Phase A: per-slot edge accumulation into accs
    {
        int d = tid & 127;
        int kg = tid >> 7;                    // 0..3 -> basis pair {2kg, 2kg+1}
        for (int s = 0; s < 4; ++s) {
            int u = u0 + s;
            int n = ucnt[u]; if (n > ECAP) n = ECAP;
            if (tid < N_REL) deg48[tid] = 0;
            if (tid < n) {
                int w = bkt[u * ECAP + tid];
                esrc[tid] = w & 0x1FFFF;
                eti[tid] = w >> 17;
            }
            __syncthreads();
            if (tid < n) atomicAdd(&deg48[eti[tid]], 1);
            __syncthreads();
            for (int ii = tid; ii < n * N_BASES; ii += BLK) {
                int i = ii >> 3, k = ii & 7;
                int t = eti[i];
                ctab[i][k] = comp[t * N_BASES + k] / (float)max(deg48[t], 1);
            }
            __syncthreads();
            float a0 = 0.0f, a1 = 0.0f;
            #pragma unroll 4
            for (int i = 0; i < n; ++i) {
                float xv = x[(size_t)esrc[i] * D + d];
                a0 += ctab[i][2 * kg] * xv;
                a1 += ctab[i][2 * kg + 1] * xv;
            }
            accs[s][(2 * kg) * D + d] = a0;
            accs[s][(2 * kg + 1) * D + d] = a1;
            __syncthreads();
        }
    }

    // Phase B: h = x@root + sum_k acc_k@B_k + bias + x
    // thread = (jq 0..31, kc 0..15); float4 weight rows feed 4 slots x 4 cols.
    {
        int jq = tid & 31, kc = tid >> 5;
        int j0 = jq * 4;
        float4 p0 = {0,0,0,0}, p1 = {0,0,0,0}, p2 = {0,0,0,0}, p3 = {0,0,0,0};
        #pragma unroll 8
        for (int ii = 0; ii < 8; ++ii) {          // root rows kc*8..+7
            int r = kc * 8 + ii;
            float4 w = *reinterpret_cast<const float4*>(root + r * D + j0);
            float a0 = xs[0][r], a1 = xs[1][r], a2 = xs[2][r], a3 = xs[3][r];
            p0.x += a0*w.x; p0.y += a0*w.y; p0.z += a0*w.z; p0.w += a0*w.w;
            p1.x += a1*w.x; p1.y += a1*w.y; p1.z += a1*w.z; p1.w += a1*w.w;
            p2.x += a2*w.x; p2.y += a2*w.y; p2.z += a2*w.z; p2.w += a2*w.w;
            p3.x += a3*w.x; p3.y += a3*w.y; p3.z += a3*w.z; p3.w += a3*w.w;
        }
        #pragma unroll 8
        for (int ii = 0; ii < 64; ++ii) {         // bases rows kc*64..+63
            int r = kc * 64 + ii;
            float4 w = *reinterpret_cast<const float4*>(bases + (size_t)r * D + j0);
            float a0 = accs[0][r], a1 = accs[1][r], a2 = accs[2][r], a3 = accs[3][r];
            p0.x += a0*w.x; p0.y += a0*w.y; p0.z += a0*w.z; p0.w += a0*w.w;
            p1.x += a1*w.x; p1.y += a1*w.y; p1.z += a1*w.z; p1.w += a1*w.w;
            p2.x += a2*w.x; p2.y += a2*w.y; p2.z += a2*w.z; p2.w += a2*w.w;
            p3.x += a3*w.x; p3.y += a3*w.y; p3.z += a3*w.z; p3.w += a3*w.w;
        }
        float* pp = part + kc * 512 + j0;         // [kc][s][128]
        pp[0]=p0.x; pp[1]=p0.y; pp[2]=p0.z; pp[3]=p0.w;  pp += 128;
        pp[0]=p1.x; pp[1]=p1.y; pp[2]=p1.z; pp[3]=p1.w;  pp += 128;
        pp[0]=p2.x; pp[1]=p2.y; pp[2]=p2.z; pp[3]=p2.w;  pp += 128;
        pp[0]=p3.x; pp[1]=p3.y; pp[2]=p3.z; pp[3]=p3.w;
    }
    __syncthreads();
    {
        int s = tid >> 7, j = tid & 127;
        float v = bias[j] + xs[s][j];
        #pragma unroll
        for (int q = 0; q < 16; ++q) v += part[q * 512 + s * 128 + j];
        hs[s][j] = v;
    }
    __syncthreads();

    // Phase C1: t1 = relu(h @ w1 + b1)   w1:[128][64]
    {
        int oq = tid & 15, kc = tid >> 4;         // kc 0..31, 4 rows each
        int o0 = oq * 4;
        float4 p0 = {0,0,0,0}, p1 = {0,0,0,0}, p2 = {0,0,0,0}, p3 = {0,0,0,0};
        #pragma unroll
        for (int ii = 0; ii < 4; ++ii) {
            int r = kc * 4 + ii;
            float4 w = *reinterpret_cast<const float4*>(w1 + r * (D / 2) + o0);
            float a0 = hs[0][r], a1 = hs[1][r], a2 = hs[2][r], a3 = hs[3][r];
            p0.x += a0*w.x; p0.y += a0*w.y; p0.z += a0*w.z; p0.w += a0*w.w;
            p1.x += a1*w.x; p1.y += a1*w.y; p1.z += a1*w.z; p1.w += a1*w.w;
            p2.x += a2*w.x; p2.y += a2*w.y; p2.z += a2*w.z; p2.w += a2*w.w;
            p3.x += a3*w.x; p3.y += a3*w.y; p3.z += a3*w.z; p3.w += a3*w.w;
        }
        float* pp = part + kc * 256 + o0;         // [kc][s][64]
        pp[0]=p0.x; pp[1]=p0.y; pp[2]=p0.z; pp[3]=p0.w;  pp += 64;
        pp[0]=p1.x; pp[1]=p1.y; pp[2]=p1.z; pp[3]=p1.w;  pp += 64;
        pp[0]=p2.x; pp[1]=p2.y; pp[2]=p2.z; pp[3]=p2.w;  pp += 64;
        pp[0]=p3.x; pp[1]=p3.y; pp[2]=p3.z; pp[3]=p3.w;
    }
    __syncthreads();
    if (tid < 256) {
        int s = tid >> 6, o = tid & 63;
        float v = b1[o];
        #pragma unroll
        for (int q = 0; q < 32; ++q) v += part[q * 256 + s * 64 + o];
        t1s[s][o] = fmaxf(v, 0.0f);
    }
    __syncthreads();

    // Phase C2: h2 = t1 @ w2 + b2 + h   w2:[64][128]
    {
        int jq = tid & 31, kc = tid >> 5;         // kc 0..15, 4 rows each
        int j0 = jq * 4;
        float4 p0 = {0,0,0,0}, p1 = {0,0,0,0}, p2 = {0,0,0,0}, p3 = {0,0,0,0};
        #pragma unroll
        for (int ii = 0; ii < 4; ++ii) {
            int r = kc * 4 + ii;
            float4 w = *reinterpret_cast<const float4*>(w2 + r * D + j0);
            float a0 = t1s[0][r], a1 = t1s[1][r], a2 = t1s[2][r], a3 = t1s[3][r];
            p0.x += a0*w.x; p0.y += a0*w.y; p0.z += a0*w.z; p0.w += a0*w.w;
            p1.x += a1*w.x; p1.y += a1*w.y; p1.z += a1*w.z; p1.w += a1*w.w;
            p2.x += a2*w.x; p2.y += a2*w.y; p2.z += a2*w.z; p2.w += a2*w.w;
            p3.x += a3*w.x; p3.y += a3*w.y; p3.z += a3*w.z; p3.w += a3*w.w;
        }
        float* pp = part + kc * 512 + j0;         // [kc][s][128]
        pp[0]=p0.x; pp[1]=p0.y; pp[2]=p0.z; pp[3]=p0.w;  pp += 128;
        pp[0]=p1.x; pp[1]=p1.y; pp[2]=p1.z; pp[3]=p1.w;  pp += 128;
        pp[0]=p2.x; pp[1]=p2.y; pp[2]=p2.z; pp[3]=p2.w;  pp += 128;
        pp[0]=p3.x; pp[1]=p3.y; pp[2]=p3.z; pp[3]=p3.w;
    }
    __syncthreads();
    {
        int s = tid >> 7, j = tid & 127;
        float v = b2[j] + hs[s][j];
        #pragma unroll
        for (int q = 0; q < 16; ++q) v += part[q * 512 + s * 128 + j];
        h2s[s][j] = v;
    }
    __syncthreads();

    // Phase C3: ent = h2 @ wp + bp   wp:[128][256]; write straight to out.
    {
        int oq = tid & 63, kc = tid >> 6;         // kc 0..7, 16 rows each
        int o0 = oq * 4;
        float4 p0 = {0,0,0,0}, p1 = {0,0,0,0}, p2 = {0,0,0,0}, p3 = {0,0,0,0};
        #pragma unroll 8
        for (int ii = 0; ii < 16; ++ii) {
            int r = kc * 16 + ii;
            float4 w = *reinterpret_cast<const float4*>(wp + r * HID + o0);
            float a0 = h2s[0][r], a1 = h2s[1][r], a2 = h2s[2][r], a3 = h2s[3][r];
            p0.x += a0*w.x; p0.y += a0*w.y; p0.z += a0*w.z; p0.w += a0*w.w;
            p1.x += a1*w.x; p1.y += a1*w.y; p1.z += a1*w.z; p1.w += a1*w.w;
            p2.x += a2*w.x; p2.y += a2*w.y; p2.z += a2*w.z; p2.w += a2*w.w;
            p3.x += a3*w.x; p3.y += a3*w.y; p3.z += a3*w.z; p3.w += a3*w.w;
        }
        float* pp = part + kc * 1024 + o0;        // [kc][s][256]
        pp[0]=p0.x; pp[1]=p0.y; pp[2]=p0.z; pp[3]=p0.w;  pp += 256;
        pp[0]=p1.x; pp[1]=p1.y; pp[2]=p1.z; pp[3]=p1.w;  pp += 256;
        pp[0]=p2.x; pp[1]=p2.y; pp[2]=p2.z; pp[3]=p2.w;  pp += 256;
        pp[0]=p3.x; pp[1]=p3.y; pp[2]=p3.z; pp[3]=p3.w;
    }
    __syncthreads();
    {
        int o = tid & 255;
        for (int s = tid >> 8; s < 4; s += 2) {
            float v = bp[o];
            #pragma unroll
            for (int q = 0; q < 8; ++q) v += part[q * 1024 + s * 256 + o];
            int np = npos4[s];
            for (int pi = 0; pi < np; ++pi)
                out[(size_t)plist4[s][pi] * HID + o] = v;
        }
    }
}

extern "C" void kernel_launch(void* const* d_in, const int* in_sizes, int n_in,
                              void* d_out, int out_size, void* d_ws, size_t ws_size,
                              hipStream_t stream) {
    const float* x     = (const float*)d_in[0];
    const float* bases = (const float*)d_in[1];
    const float* comp  = (const float*)d_in[2];
    const float* root  = (const float*)d_in[3];
    const float* bias  = (const float*)d_in[4];
    const float* w1    = (const float*)d_in[5];
    const float* b1    = (const float*)d_in[6];
    const float* w2    = (const float*)d_in[7];
    const float* b2    = (const float*)d_in[8];
    const float* wp    = (const float*)d_in[9];
    const float* bp    = (const float*)d_in[10];
    const int* eidx    = (const int*)d_in[11];
    const int* srcp    = eidx;
    const int* dstp    = eidx + N_EDGES;
    const int* etype   = (const int*)d_in[12];
    const int* eids    = (const int*)d_in[13];
    float* out = (float*)d_out;
    int* ws = (int*)d_ws;

    void* args[] = {
        (void*)&srcp, (void*)&dstp, (void*)&etype, (void*)&eids,
        (void*)&x, (void*)&comp, (void*)&bases, (void*)&root,
        (void*)&bias, (void*)&w1, (void*)&b1, (void*)&w2,
        (void*)&b2, (void*)&wp, (void*)&bp, (void*)&ws, (void*)&out
    };
    hipLaunchCooperativeKernel((void*)k_mega, dim3(GRIDSZ), dim3(BLK),
                               args, 0, stream);
}

// Round 8
// 140.728 us; speedup vs baseline: 1.6943x; 1.6943x over previous
//
#include <hip/hip_runtime.h>

#define N_ENTITY 100000
#define D 128
#define HID 256
#define N_REL 48
#define N_BASES 8
#define N_EDGES 1000000
#define NPOS 1024
#define ECAP 96          // bucket capacity per slot (max in-deg of ~1019 targets ~35)
#define PCAP 16          // max duplicate positions per entity

// ws layout in 4-byte elements
#define OFF_MAP    0         // int[100032]  memset 0x7F
#define OFF_BITMAP 100032    // int[3200]    cleared in k_register
#define OFF_UCNT   103232    // int[1024]    cleared in k_register
#define OFF_PCNT   104256    // int[1024]    cleared in k_register
#define OFF_PBUF   105280    // int[1024*PCAP]
#define OFF_BKT    121664    // int[1024*ECAP] packed (src | type<<17)
// end = 219968 ints ~ 0.88 MB

__global__ void k_register(const int* __restrict__ eids, int* __restrict__ map,
                           unsigned int* __restrict__ bitmap, int* __restrict__ ucnt,
                           int* __restrict__ pcnt, int* __restrict__ pbuf) {
    int tid = threadIdx.x;                 // blockDim = 1024, single block
    for (int i = tid; i < 3200; i += 1024) bitmap[i] = 0u;
    ucnt[tid] = 0;
    pcnt[tid] = 0;
    __syncthreads();
    int e = eids[tid];
    atomicMin(&map[e], tid);
    atomicOr(&bitmap[e >> 5], 1u << (e & 31));
    __syncthreads();
    int u = map[e];                        // owner slot for this position
    int q = atomicAdd(&pcnt[u], 1);
    if (q < PCAP) pbuf[u * PCAP + q] = tid;
}

// scan 1M edges (4 per thread): bitmap filter (L1-resident); matches go
// straight into fixed-capacity per-slot buckets. Atomics spread over 1024 addrs.
__global__ __launch_bounds__(256) void k_count(
        const int* __restrict__ src, const int* __restrict__ dst,
        const int* __restrict__ etype, const int* __restrict__ map,
        const unsigned int* __restrict__ bitmap, int* __restrict__ ucnt,
        int* __restrict__ bkt) {
    int base = (blockIdx.x * 256 + threadIdx.x) * 4;
    if (base >= N_EDGES) return;
    const int4 d4 = *reinterpret_cast<const int4*>(dst + base);
    #pragma unroll
    for (int q = 0; q < 4; ++q) {
        int d = (&d4.x)[q];
        if ((bitmap[d >> 5] >> (d & 31)) & 1u) {
            int e = base + q;
            int u = map[d];
            int pos = atomicAdd(&ucnt[u], 1);
            if (pos < ECAP)
                bkt[u * ECAP + pos] = src[e] | (etype[e] << 17);
        }
    }
}

// Fused RGCN + MLP + projection. BM=4 slots/block, 256 blocks x 512 threads.
// A-matrix [4][1152] = (x-row || 8 basis-acc rows) in LDS; all weight streams
// are float4 rows, each feeding 16 FMAs (4 slots x 4 cols). Writes d_out
// directly via per-slot position lists. LDS pool: A region reused as K-split
// partial buffer after Phase B's K-loop.
__global__ __launch_bounds__(512) void k_fused(
        const int* __restrict__ eids, const int* __restrict__ ucnt,
        const int* __restrict__ pcnt, const int* __restrict__ pbuf,
        const int* __restrict__ bkt, const float* __restrict__ x,
        const float* __restrict__ comp, const float* __restrict__ bases,
        const float* __restrict__ root, const float* __restrict__ bias,
        const float* __restrict__ w1, const float* __restrict__ b1,
        const float* __restrict__ w2, const float* __restrict__ b2,
        const float* __restrict__ wp, const float* __restrict__ bp,
        float* __restrict__ out) {
    __shared__ float smem[8192];            // 32 KB: A[4][1152] then partials
    __shared__ float hs4[4 * 128];
    __shared__ float t1s4[4 * 64];
    __shared__ float h2s4[4 * 128];
    __shared__ float comp_s[N_REL * N_BASES];   // 384
    __shared__ int deg4[4 * N_REL];
    __shared__ int esrc4[4][ECAP], eti4[4][ECAP];
    __shared__ int enames4[4], ncnt4[4], npos4[4], plist4[4][PCAP];

    int tid = threadIdx.x;
    int u0 = blockIdx.x * 4;

    if (tid < 4) {
        enames4[tid] = eids[u0 + tid];
        int c = ucnt[u0 + tid];  ncnt4[tid] = c < ECAP ? c : ECAP;
        int p = pcnt[u0 + tid];  npos4[tid] = p < PCAP ? p : PCAP;
    }
    if (tid < 4 * PCAP) {
        int s = tid >> 4, q = tid & (PCAP - 1);
        plist4[s][q] = pbuf[(u0 + s) * PCAP + q];
    }
    if (tid < N_REL * N_BASES) comp_s[tid] = comp[tid];
    if (tid < 4 * N_REL) deg4[tid] = 0;
    __syncthreads();

    // ---- Phase A: bucket load, degrees, basis-weighted accumulation ----
    {
        int s = tid >> 7, i = tid & 127;
        if (i < ncnt4[s]) {
            int w = bkt[(u0 + s) * ECAP + i];
            esrc4[s][i] = w & 0x1FFFF;
            eti4[s][i] = w >> 17;
        }
        smem[s * 1152 + i] = x[(size_t)enames4[s] * D + i];   // A[s][0..127] = x row
    }
    __syncthreads();
    if (tid < 4 * ECAP) {
        int s = tid / ECAP, i = tid - s * ECAP;
        if (i < ncnt4[s]) atomicAdd(&deg4[s * N_REL + eti4[s][i]], 1);
    }
    __syncthreads();
    {
        int dd = tid & 127, s = tid >> 7;
        float a[8] = {0, 0, 0, 0, 0, 0, 0, 0};
        int n = ncnt4[s];
        #pragma unroll 4
        for (int i = 0; i < n; ++i) {
            int t = eti4[s][i];
            float rn = 1.0f / (float)max(deg4[s * N_REL + t], 1);
            float xv = x[(size_t)esrc4[s][i] * D + dd];
            #pragma unroll
            for (int k = 0; k < 8; ++k) a[k] += comp_s[t * 8 + k] * rn * xv;
        }
        #pragma unroll
        for (int k = 0; k < 8; ++k)
            smem[s * 1152 + 128 + k * 128 + dd] = a[k];       // A[s][128+k*128+d]
    }
    __syncthreads();

    // ---- Phase B: h = A @ [root; bases] + bias + x ----
    // thread = (jq 0..31, kc 0..15): 4 cols, 72 K-rows. 16 FMA per float4.
    {
        int jq = tid & 31, kc = tid >> 5;
        int j0 = jq * 4;
        float4 p0 = {0,0,0,0}, p1 = {0,0,0,0}, p2 = {0,0,0,0}, p3 = {0,0,0,0};
        int r0 = kc * 72;
        #pragma unroll 4
        for (int ii = 0; ii < 72; ++ii) {
            int r = r0 + ii;
            const float* wrow = (r < 128) ? (root + (size_t)r * D)
                                          : (bases + (size_t)(r - 128) * D);
            float4 w = *reinterpret_cast<const float4*>(wrow + j0);
            float a0 = smem[0 * 1152 + r], a1 = smem[1 * 1152 + r];
            float a2 = smem[2 * 1152 + r], a3 = smem[3 * 1152 + r];
            p0.x += a0*w.x; p0.y += a0*w.y; p0.z += a0*w.z; p0.w += a0*w.w;
            p1.x += a1*w.x; p1.y += a1*w.y; p1.z += a1*w.z; p1.w += a1*w.w;
            p2.x += a2*w.x; p2.y += a2*w.y; p2.z += a2*w.z; p2.w += a2*w.w;
            p3.x += a3*w.x; p3.y += a3*w.y; p3.z += a3*w.z; p3.w += a3*w.w;
        }
        __syncthreads();                       // A region dead; safe to clobber
        *reinterpret_cast<float4*>(&smem[kc * 512 +   0 + j0]) = p0;
        *reinterpret_cast<float4*>(&smem[kc * 512 + 128 + j0]) = p1;
        *reinterpret_cast<float4*>(&smem[kc * 512 + 256 + j0]) = p2;
        *reinterpret_cast<float4*>(&smem[kc * 512 + 384 + j0]) = p3;
    }
    __syncthreads();
    {
        int s = tid >> 7, j = tid & 127;
        float v = bias[j] + x[(size_t)enames4[s] * D + j];    // bias + residual
        #pragma unroll
        for (int q = 0; q < 16; ++q) v += smem[q * 512 + s * 128 + j];
        hs4[s * 128 + j] = v;
    }
    __syncthreads();

    // ---- Phase C1: t1 = relu(h @ w1 + b1)   w1:[128][64] ----
    {
        int oq = tid & 15, kc = tid >> 4;      // kc 0..31, 4 rows each
        int o0 = oq * 4;
        float4 p0 = {0,0,0,0}, p1 = {0,0,0,0}, p2 = {0,0,0,0}, p3 = {0,0,0,0};
        #pragma unroll
        for (int ii = 0; ii < 4; ++ii) {
            int r = kc * 4 + ii;
            float4 w = *reinterpret_cast<const float4*>(w1 + (size_t)r * (D/2) + o0);
            float a0 = hs4[0*128 + r], a1 = hs4[1*128 + r];
            float a2 = hs4[2*128 + r], a3 = hs4[3*128 + r];
            p0.x += a0*w.x; p0.y += a0*w.y; p0.z += a0*w.z; p0.w += a0*w.w;
            p1.x += a1*w.x; p1.y += a1*w.y; p1.z += a1*w.z; p1.w += a1*w.w;
            p2.x += a2*w.x; p2.y += a2*w.y; p2.z += a2*w.z; p2.w += a2*w.w;
            p3.x += a3*w.x; p3.y += a3*w.y; p3.z += a3*w.z; p3.w += a3*w.w;
        }
        *reinterpret_cast<float4*>(&smem[kc * 256 +   0 + o0]) = p0;
        *reinterpret_cast<float4*>(&smem[kc * 256 +  64 + o0]) = p1;
        *reinterpret_cast<float4*>(&smem[kc * 256 + 128 + o0]) = p2;
        *reinterpret_cast<float4*>(&smem[kc * 256 + 192 + o0]) = p3;
    }
    __syncthreads();
    if (tid < 256) {
        int s = tid >> 6, o = tid & 63;
        float v = b1[o];
        #pragma unroll
        for (int q = 0; q < 32; ++q) v += smem[q * 256 + s * 64 + o];
        t1s4[s * 64 + o] = fmaxf(v, 0.0f);
    }
    __syncthreads();

    // ---- Phase C2: h2 = t1 @ w2 + b2 + h   w2:[64][128] ----
    {
        int jq = tid & 31, kc = tid >> 5;      // kc 0..15, 4 rows each
        int j0 = jq * 4;
        float4 p0 = {0,0,0,0}, p1 = {0,0,0,0}, p2 = {0,0,0,0}, p3 = {0,0,0,0};
        #pragma unroll
        for (int ii = 0; ii < 4; ++ii) {
            int r = kc * 4 + ii;
            float4 w = *reinterpret_cast<const float4*>(w2 + (size_t)r * D + j0);
            float a0 = t1s4[0*64 + r], a1 = t1s4[1*64 + r];
            float a2 = t1s4[2*64 + r], a3 = t1s4[3*64 + r];
            p0.x += a0*w.x; p0.y += a0*w.y; p0.z += a0*w.z; p0.w += a0*w.w;
            p1.x += a1*w.x; p1.y += a1*w.y; p1.z += a1*w.z; p1.w += a1*w.w;
            p2.x += a2*w.x; p2.y += a2*w.y; p2.z += a2*w.z; p2.w += a2*w.w;
            p3.x += a3*w.x; p3.y += a3*w.y; p3.z += a3*w.z; p3.w += a3*w.w;
        }
        *reinterpret_cast<float4*>(&smem[kc * 512 +   0 + j0]) = p0;
        *reinterpret_cast<float4*>(&smem[kc * 512 + 128 + j0]) = p1;
        *reinterpret_cast<float4*>(&smem[kc * 512 + 256 + j0]) = p2;
        *reinterpret_cast<float4*>(&smem[kc * 512 + 384 + j0]) = p3;
    }
    __syncthreads();
    {
        int s = tid >> 7, j = tid & 127;
        float v = b2[j] + hs4[s * 128 + j];
        #pragma unroll
        for (int q = 0; q < 16; ++q) v += smem[q * 512 + s * 128 + j];
        h2s4[s * 128 + j] = v;
    }
    __syncthreads();

    // ---- Phase C3: ent = h2 @ wp + bp   wp:[128][256]; write out direct ----
    {
        int oq = tid & 63, kc = tid >> 6;      // kc 0..7, 16 rows each
        int o0 = oq * 4;
        float4 p0 = {0,0,0,0}, p1 = {0,0,0,0}, p2 = {0,0,0,0}, p3 = {0,0,0,0};
        #pragma unroll 8
        for (int ii = 0; ii < 16; ++ii) {
            int r = kc * 16 + ii;
            float4 w = *reinterpret_cast<const float4*>(wp + (size_t)r * HID + o0);
            float a0 = h2s4[0*128 + r], a1 = h2s4[1*128 + r];
            float a2 = h2s4[2*128 + r], a3 = h2s4[3*128 + r];
            p0.x += a0*w.x; p0.y += a0*w.y; p0.z += a0*w.z; p0.w += a0*w.w;
            p1.x += a1*w.x; p1.y += a1*w.y; p1.z += a1*w.z; p1.w += a1*w.w;
            p2.x += a2*w.x; p2.y += a2*w.y; p2.z += a2*w.z; p2.w += a2*w.w;
            p3.x += a3*w.x; p3.y += a3*w.y; p3.z += a3*w.z; p3.w += a3*w.w;
        }
        *reinterpret_cast<float4*>(&smem[kc * 1024 +   0 + o0]) = p0;
        *reinterpret_cast<float4*>(&smem[kc * 1024 + 256 + o0]) = p1;
        *reinterpret_cast<float4*>(&smem[kc * 1024 + 512 + o0]) = p2;
        *reinterpret_cast<float4*>(&smem[kc * 1024 + 768 + o0]) = p3;
    }
    __syncthreads();
    {
        int o = tid & 255, sb = tid >> 8;
        #pragma unroll
        for (int si = 0; si < 2; ++si) {
            int s = sb + si * 2;
            float v = bp[o];
            #pragma unroll
            for (int q = 0; q < 8; ++q) v += smem[q * 1024 + s * 256 + o];
            int np = npos4[s];
            for (int pi = 0; pi < np; ++pi)
                out[(size_t)plist4[s][pi] * HID + o] = v;
        }
    }
}

extern "C" void kernel_launch(void* const* d_in, const int* in_sizes, int n_in,
                              void* d_out, int out_size, void* d_ws, size_t ws_size,
                              hipStream_t stream) {
    const float* x     = (const float*)d_in[0];
    const float* bases = (const float*)d_in[1];
    const float* comp  = (const float*)d_in[2];
    const float* root  = (const float*)d_in[3];
    const float* bias  = (const float*)d_in[4];
    const float* w1    = (const float*)d_in[5];
    const float* b1    = (const float*)d_in[6];
    const float* w2    = (const float*)d_in[7];
    const float* b2    = (const float*)d_in[8];
    const float* wp    = (const float*)d_in[9];
    const float* bp    = (const float*)d_in[10];
    const int* eidx    = (const int*)d_in[11];
    const int* srcp    = eidx;
    const int* dstp    = eidx + N_EDGES;
    const int* etype   = (const int*)d_in[12];
    const int* eids    = (const int*)d_in[13];
    float* out = (float*)d_out;

    int* ws = (int*)d_ws;
    int* map            = ws + OFF_MAP;
    unsigned int* bmap  = (unsigned int*)(ws + OFF_BITMAP);
    int* ucnt           = ws + OFF_UCNT;
    int* pcnt           = ws + OFF_PCNT;
    int* pbuf           = ws + OFF_PBUF;
    int* bkt            = ws + OFF_BKT;

    hipMemsetAsync(map, 0x7F, (size_t)100032 * sizeof(int), stream);

    k_register<<<1, NPOS, 0, stream>>>(eids, map, bmap, ucnt, pcnt, pbuf);
    k_count<<<(N_EDGES / 4 + 255) / 256, 256, 0, stream>>>(srcp, dstp, etype, map,
                                                           bmap, ucnt, bkt);
    k_fused<<<NPOS / 4, 512, 0, stream>>>(eids, ucnt, pcnt, pbuf, bkt, x, comp,
                                          bases, root, bias, w1, b1, w2, b2,
                                          wp, bp, out);
}

// Round 9
// 136.249 us; speedup vs baseline: 1.7500x; 1.0329x over previous
//
#include <hip/hip_runtime.h>

#define N_ENTITY 100000
#define D 128
#define HID 256
#define N_REL 48
#define N_BASES 8
#define N_EDGES 1000000
#define NPOS 1024
#define ECAP 96          // bucket capacity per slot (max in-deg of ~1019 targets ~35)
#define PCAP 16          // max duplicate positions per entity

// ws layout in 4-byte elements (no memset needed: map is bitmap-gated)
#define OFF_MAP    0         // int[100032]  NEVER cleared (bitmap gates validity)
#define OFF_BITMAP 100032    // int[3200]    cleared in k_register
#define OFF_UCNT   103232    // int[1024]    cleared in k_register
#define OFF_PCNT   104256    // int[1024]    cleared in k_register
#define OFF_PBUF   105280    // int[1024*PCAP]
#define OFF_BKT    121664    // int[1024*ECAP] packed (src | type<<17)
// end = 219968 ints ~ 0.88 MB

__global__ void k_register(const int* __restrict__ eids, int* __restrict__ map,
                           unsigned int* __restrict__ bitmap, int* __restrict__ ucnt,
                           int* __restrict__ pcnt, int* __restrict__ pbuf) {
    int tid = threadIdx.x;                 // blockDim = 1024, single block
    for (int i = tid; i < 3200; i += 1024) bitmap[i] = 0u;
    ucnt[tid] = 0;
    pcnt[tid] = 0;
    int e = eids[tid];
    map[e] = tid;          // racing plain store: any single winner is a valid owner
    __syncthreads();       // map stores + clears visible block-wide (same CU/L1)
    atomicOr(&bitmap[e >> 5], 1u << (e & 31));
    int u = map[e];        // winner slot for this entity
    int q = atomicAdd(&pcnt[u], 1);
    if (q < PCAP) pbuf[u * PCAP + q] = tid;
}

// scan 1M edges (4 per thread): bitmap filter (L1-resident); matches go
// straight into fixed-capacity per-slot buckets. Atomics spread over 1024 addrs.
__global__ __launch_bounds__(256) void k_count(
        const int* __restrict__ src, const int* __restrict__ dst,
        const int* __restrict__ etype, const int* __restrict__ map,
        const unsigned int* __restrict__ bitmap, int* __restrict__ ucnt,
        int* __restrict__ bkt) {
    int base = (blockIdx.x * 256 + threadIdx.x) * 4;
    if (base >= N_EDGES) return;
    const int4 d4 = *reinterpret_cast<const int4*>(dst + base);
    #pragma unroll
    for (int q = 0; q < 4; ++q) {
        int d = (&d4.x)[q];
        if ((bitmap[d >> 5] >> (d & 31)) & 1u) {
            int e = base + q;
            int u = map[d];
            int pos = atomicAdd(&ucnt[u], 1);
            if (pos < ECAP)
                bkt[u * ECAP + pos] = src[e] | (etype[e] << 17);
        }
    }
}

// Fused RGCN + MLP + projection. BM=4 slots/block, 256 blocks x 512 threads.
// A-matrix [4][1152] = (x-row || 8 basis-acc rows) in LDS; all weight streams
// are float4 rows, each feeding 16 FMAs (4 slots x 4 cols). Writes d_out
// directly via per-slot position lists.
__global__ __launch_bounds__(512) void k_fused(
        const int* __restrict__ eids, const int* __restrict__ ucnt,
        const int* __restrict__ pcnt, const int* __restrict__ pbuf,
        const int* __restrict__ bkt, const float* __restrict__ x,
        const float* __restrict__ comp, const float* __restrict__ bases,
        const float* __restrict__ root, const float* __restrict__ bias,
        const float* __restrict__ w1, const float* __restrict__ b1,
        const float* __restrict__ w2, const float* __restrict__ b2,
        const float* __restrict__ wp, const float* __restrict__ bp,
        float* __restrict__ out) {
    __shared__ float smem[8192];            // 32 KB: A[4][1152] then partials
    __shared__ float hs4[4 * 128];
    __shared__ float t1s4[4 * 64];
    __shared__ float h2s4[4 * 128];
    __shared__ float comp_s[N_REL * N_BASES];   // 384
    __shared__ int deg4[4 * N_REL];
    __shared__ int esrc4[4][ECAP], eti4[4][ECAP];
    __shared__ int enames4[4], ncnt4[4], npos4[4], plist4[4][PCAP];

    int tid = threadIdx.x;
    int u0 = blockIdx.x * 4;

    if (tid < 4) {
        enames4[tid] = eids[u0 + tid];
        int c = ucnt[u0 + tid];  ncnt4[tid] = c < ECAP ? c : ECAP;
        int p = pcnt[u0 + tid];  npos4[tid] = p < PCAP ? p : PCAP;
    }
    if (tid < 4 * PCAP) {
        int s = tid >> 4, q = tid & (PCAP - 1);
        plist4[s][q] = pbuf[(u0 + s) * PCAP + q];
    }
    if (tid < N_REL * N_BASES) comp_s[tid] = comp[tid];
    if (tid < 4 * N_REL) deg4[tid] = 0;
    __syncthreads();

    // ---- Phase A: bucket load, degrees, basis-weighted accumulation ----
    {
        int s = tid >> 7, i = tid & 127;
        if (i < ncnt4[s]) {
            int w = bkt[(u0 + s) * ECAP + i];
            esrc4[s][i] = w & 0x1FFFF;
            eti4[s][i] = w >> 17;
        }
        smem[s * 1152 + i] = x[(size_t)enames4[s] * D + i];   // A[s][0..127] = x row
    }
    __syncthreads();
    if (tid < 4 * ECAP) {
        int s = tid / ECAP, i = tid - s * ECAP;
        if (i < ncnt4[s]) atomicAdd(&deg4[s * N_REL + eti4[s][i]], 1);
    }
    __syncthreads();
    {
        int dd = tid & 127, s = tid >> 7;
        float a[8] = {0, 0, 0, 0, 0, 0, 0, 0};
        int n = ncnt4[s];
        #pragma unroll 4
        for (int i = 0; i < n; ++i) {
            int t = eti4[s][i];
            float rn = 1.0f / (float)max(deg4[s * N_REL + t], 1);
            float xv = x[(size_t)esrc4[s][i] * D + dd];
            #pragma unroll
            for (int k = 0; k < 8; ++k) a[k] += comp_s[t * 8 + k] * rn * xv;
        }
        #pragma unroll
        for (int k = 0; k < 8; ++k)
            smem[s * 1152 + 128 + k * 128 + dd] = a[k];       // A[s][128+k*128+d]
    }
    __syncthreads();

    // ---- Phase B: h = A @ [root; bases] + bias + x ----
    // thread = (jq 0..31, kc 0..15): 4 cols; 8 root rows + 64 bases rows.
    {
        int jq = tid & 31, kc = tid >> 5;
        int j0 = jq * 4;
        float4 p0 = {0,0,0,0}, p1 = {0,0,0,0}, p2 = {0,0,0,0}, p3 = {0,0,0,0};
        #pragma unroll 8
        for (int ii = 0; ii < 8; ++ii) {          // root rows kc*8..+7
            int r = kc * 8 + ii;
            float4 w = *reinterpret_cast<const float4*>(root + (size_t)r * D + j0);
            float a0 = smem[0 * 1152 + r], a1 = smem[1 * 1152 + r];
            float a2 = smem[2 * 1152 + r], a3 = smem[3 * 1152 + r];
            p0.x += a0*w.x; p0.y += a0*w.y; p0.z += a0*w.z; p0.w += a0*w.w;
            p1.x += a1*w.x; p1.y += a1*w.y; p1.z += a1*w.z; p1.w += a1*w.w;
            p2.x += a2*w.x; p2.y += a2*w.y; p2.z += a2*w.z; p2.w += a2*w.w;
            p3.x += a3*w.x; p3.y += a3*w.y; p3.z += a3*w.z; p3.w += a3*w.w;
        }
        #pragma unroll 8
        for (int ii = 0; ii < 64; ++ii) {         // bases rows kc*64..+63
            int r = kc * 64 + ii;
            float4 w = *reinterpret_cast<const float4*>(bases + (size_t)r * D + j0);
            float a0 = smem[0 * 1152 + 128 + r], a1 = smem[1 * 1152 + 128 + r];
            float a2 = smem[2 * 1152 + 128 + r], a3 = smem[3 * 1152 + 128 + r];
            p0.x += a0*w.x; p0.y += a0*w.y; p0.z += a0*w.z; p0.w += a0*w.w;
            p1.x += a1*w.x; p1.y += a1*w.y; p1.z += a1*w.z; p1.w += a1*w.w;
            p2.x += a2*w.x; p2.y += a2*w.y; p2.z += a2*w.z; p2.w += a2*w.w;
            p3.x += a3*w.x; p3.y += a3*w.y; p3.z += a3*w.z; p3.w += a3*w.w;
        }
        __syncthreads();                       // A region dead; safe to clobber
        *reinterpret_cast<float4*>(&smem[kc * 512 +   0 + j0]) = p0;
        *reinterpret_cast<float4*>(&smem[kc * 512 + 128 + j0]) = p1;
        *reinterpret_cast<float4*>(&smem[kc * 512 + 256 + j0]) = p2;
        *reinterpret_cast<float4*>(&smem[kc * 512 + 384 + j0]) = p3;
    }
    __syncthreads();
    {
        int s = tid >> 7, j = tid & 127;
        float v = bias[j] + x[(size_t)enames4[s] * D + j];    // bias + residual
        #pragma unroll
        for (int q = 0; q < 16; ++q) v += smem[q * 512 + s * 128 + j];
        hs4[s * 128 + j] = v;
    }
    __syncthreads();

    // ---- Phase C1: t1 = relu(h @ w1 + b1)   w1:[128][64] ----
    {
        int oq = tid & 15, kc = tid >> 4;      // kc 0..31, 4 rows each
        int o0 = oq * 4;
        float4 p0 = {0,0,0,0}, p1 = {0,0,0,0}, p2 = {0,0,0,0}, p3 = {0,0,0,0};
        #pragma unroll
        for (int ii = 0; ii < 4; ++ii) {
            int r = kc * 4 + ii;
            float4 w = *reinterpret_cast<const float4*>(w1 + (size_t)r * (D/2) + o0);
            float a0 = hs4[0*128 + r], a1 = hs4[1*128 + r];
            float a2 = hs4[2*128 + r], a3 = hs4[3*128 + r];
            p0.x += a0*w.x; p0.y += a0*w.y; p0.z += a0*w.z; p0.w += a0*w.w;
            p1.x += a1*w.x; p1.y += a1*w.y; p1.z += a1*w.z; p1.w += a1*w.w;
            p2.x += a2*w.x; p2.y += a2*w.y; p2.z += a2*w.z; p2.w += a2*w.w;
            p3.x += a3*w.x; p3.y += a3*w.y; p3.z += a3*w.z; p3.w += a3*w.w;
        }
        *reinterpret_cast<float4*>(&smem[kc * 256 +   0 + o0]) = p0;
        *reinterpret_cast<float4*>(&smem[kc * 256 +  64 + o0]) = p1;
        *reinterpret_cast<float4*>(&smem[kc * 256 + 128 + o0]) = p2;
        *reinterpret_cast<float4*>(&smem[kc * 256 + 192 + o0]) = p3;
    }
    __syncthreads();
    if (tid < 256) {
        int s = tid >> 6, o = tid & 63;
        float v = b1[o];
        #pragma unroll
        for (int q = 0; q < 32; ++q) v += smem[q * 256 + s * 64 + o];
        t1s4[s * 64 + o] = fmaxf(v, 0.0f);
    }
    __syncthreads();

    // ---- Phase C2: h2 = t1 @ w2 + b2 + h   w2:[64][128] ----
    {
        int jq = tid & 31, kc = tid >> 5;      // kc 0..15, 4 rows each
        int j0 = jq * 4;
        float4 p0 = {0,0,0,0}, p1 = {0,0,0,0}, p2 = {0,0,0,0}, p3 = {0,0,0,0};
        #pragma unroll
        for (int ii = 0; ii < 4; ++ii) {
            int r = kc * 4 + ii;
            float4 w = *reinterpret_cast<const float4*>(w2 + (size_t)r * D + j0);
            float a0 = t1s4[0*64 + r], a1 = t1s4[1*64 + r];
            float a2 = t1s4[2*64 + r], a3 = t1s4[3*64 + r];
            p0.x += a0*w.x; p0.y += a0*w.y; p0.z += a0*w.z; p0.w += a0*w.w;
            p1.x += a1*w.x; p1.y += a1*w.y; p1.z += a1*w.z; p1.w += a1*w.w;
            p2.x += a2*w.x; p2.y += a2*w.y; p2.z += a2*w.z; p2.w += a2*w.w;
            p3.x += a3*w.x; p3.y += a3*w.y; p3.z += a3*w.z; p3.w += a3*w.w;
        }
        *reinterpret_cast<float4*>(&smem[kc * 512 +   0 + j0]) = p0;
        *reinterpret_cast<float4*>(&smem[kc * 512 + 128 + j0]) = p1;
        *reinterpret_cast<float4*>(&smem[kc * 512 + 256 + j0]) = p2;
        *reinterpret_cast<float4*>(&smem[kc * 512 + 384 + j0]) = p3;
    }
    __syncthreads();
    {
        int s = tid >> 7, j = tid & 127;
        float v = b2[j] + hs4[s * 128 + j];
        #pragma unroll
        for (int q = 0; q < 16; ++q) v += smem[q * 512 + s * 128 + j];
        h2s4[s * 128 + j] = v;
    }
    __syncthreads();

    // ---- Phase C3: ent = h2 @ wp + bp   wp:[128][256]; write out direct ----
    {
        int oq = tid & 63, kc = tid >> 6;      // kc 0..7, 16 rows each
        int o0 = oq * 4;
        float4 p0 = {0,0,0,0}, p1 = {0,0,0,0}, p2 = {0,0,0,0}, p3 = {0,0,0,0};
        #pragma unroll 8
        for (int ii = 0; ii < 16; ++ii) {
            int r = kc * 16 + ii;
            float4 w = *reinterpret_cast<const float4*>(wp + (size_t)r * HID + o0);
            float a0 = h2s4[0*128 + r], a1 = h2s4[1*128 + r];
            float a2 = h2s4[2*128 + r], a3 = h2s4[3*128 + r];
            p0.x += a0*w.x; p0.y += a0*w.y; p0.z += a0*w.z; p0.w += a0*w.w;
            p1.x += a1*w.x; p1.y += a1*w.y; p1.z += a1*w.z; p1.w += a1*w.w;
            p2.x += a2*w.x; p2.y += a2*w.y; p2.z += a2*w.z; p2.w += a2*w.w;
            p3.x += a3*w.x; p3.y += a3*w.y; p3.z += a3*w.z; p3.w += a3*w.w;
        }
        *reinterpret_cast<float4*>(&smem[kc * 1024 +   0 + o0]) = p0;
        *reinterpret_cast<float4*>(&smem[kc * 1024 + 256 + o0]) = p1;
        *reinterpret_cast<float4*>(&smem[kc * 1024 + 512 + o0]) = p2;
        *reinterpret_cast<float4*>(&smem[kc * 1024 + 768 + o0]) = p3;
    }
    __syncthreads();
    {
        int o = tid & 255, sb = tid >> 8;
        #pragma unroll
        for (int si = 0; si < 2; ++si) {
            int s = sb + si * 2;
            float v = bp[o];
            #pragma unroll
            for (int q = 0; q < 8; ++q) v += smem[q * 1024 + s * 256 + o];
            int np = npos4[s];
            for (int pi = 0; pi < np; ++pi)
                out[(size_t)plist4[s][pi] * HID + o] = v;
        }
    }
}

extern "C" void kernel_launch(void* const* d_in, const int* in_sizes, int n_in,
                              void* d_out, int out_size, void* d_ws, size_t ws_size,
                              hipStream_t stream) {
    const float* x     = (const float*)d_in[0];
    const float* bases = (const float*)d_in[1];
    const float* comp  = (const float*)d_in[2];
    const float* root  = (const float*)d_in[3];
    const float* bias  = (const float*)d_in[4];
    const float* w1    = (const float*)d_in[5];
    const float* b1    = (const float*)d_in[6];
    const float* w2    = (const float*)d_in[7];
    const float* b2    = (const float*)d_in[8];
    const float* wp    = (const float*)d_in[9];
    const float* bp    = (const float*)d_in[10];
    const int* eidx    = (const int*)d_in[11];
    const int* srcp    = eidx;
    const int* dstp    = eidx + N_EDGES;
    const int* etype   = (const int*)d_in[12];
    const int* eids    = (const int*)d_in[13];
    float* out = (float*)d_out;

    int* ws = (int*)d_ws;
    int* map            = ws + OFF_MAP;
    unsigned int* bmap  = (unsigned int*)(ws + OFF_BITMAP);
    int* ucnt           = ws + OFF_UCNT;
    int* pcnt           = ws + OFF_PCNT;
    int* pbuf           = ws + OFF_PBUF;
    int* bkt            = ws + OFF_BKT;

    k_register<<<1, NPOS, 0, stream>>>(eids, map, bmap, ucnt, pcnt, pbuf);
    k_count<<<(N_EDGES / 4 + 255) / 256, 256, 0, stream>>>(srcp, dstp, etype, map,
                                                           bmap, ucnt, bkt);
    k_fused<<<NPOS / 4, 512, 0, stream>>>(eids, ucnt, pcnt, pbuf, bkt, x, comp,
                                          bases, root, bias, w1, b1, w2, b2,
                                          wp, bp, out);
}